// Round 13
// baseline (47.318 us; speedup 1.0000x reference)
//
#include <hip/hip_runtime.h>
#include <math.h>

// Problem constants (D_IN == D_OUT == 4096)
constexpr int   D     = 4096;
constexpr float ALPHA = 0.001f;   // heb_lr
constexpr float GAMMA = 0.99f;
constexpr float EPSC  = 0.0001f;

// --- main path decomposition ---
constexpr int RG    = 8;               // rows per k_gz block (P granularity)
constexpr int NPR   = D / RG;          // 512 P rows
constexpr int SUB   = 4;               // rows per LDS sub-batch (64 KB tile)
constexpr int GSZ2  = 16;              // P rows per supersum group
constexpr int NSS   = NPR / GSZ2;      // 32 SS rows
constexpr int RCH3  = 32;              // k_update rows per chunk
constexpr int NCH3  = D / RCH3;        // 128 -> 512 blocks
constexpr int TPB3  = 256;

using vf4 = float __attribute__((ext_vector_type(4)));

// ---------------------------------------------------------------------------
// K1 (R12-proven, unchanged): fused GEMV + chunk column-partials via LDS
// staging (z-units), register prefetch of sub-batch 1 under sub-batch 0's
// LDS accumulate. Plain P stores (agent-scope atomics are the pinned R10
// regression cause). W read from HBM exactly once.
// ---------------------------------------------------------------------------
__global__ __launch_bounds__(256, 2) void k_gz(const float* __restrict__ W,
                                               const float* __restrict__ x,
                                               const float* __restrict__ b,
                                               float* __restrict__ z_out,
                                               float* __restrict__ P) {
    const int tid  = threadIdx.x;
    const int lane = tid & 63;
    const int wv   = tid >> 6;            // 0..3
    const int c    = blockIdx.x;          // P row (8-row chunk)
    const int k0   = c * RG;

    __shared__ float4 tile[SUB * 1024];   // 64 KB
    __shared__ float  sz[SUB];

    const float4* xv = reinterpret_cast<const float4*>(x);
    float4 acc[4] = {make_float4(0.f, 0.f, 0.f, 0.f),
                     make_float4(0.f, 0.f, 0.f, 0.f),
                     make_float4(0.f, 0.f, 0.f, 0.f),
                     make_float4(0.f, 0.f, 0.f, 0.f)};

    // ---- Stage A: sub-batch 0 -> tile + dot ----
    {
        const int row = k0 + wv;
        const float4* Wr = reinterpret_cast<const float4*>(W + (size_t)row * D);
        float a = 0.f;
        #pragma unroll
        for (int q = 0; q < 16; ++q) {
            const float4 w = Wr[lane + q * 64];
            tile[wv * 1024 + lane + q * 64] = w;
            const float4 xx = xv[lane + q * 64];
            a += w.x * xx.x + w.y * xx.y + w.z * xx.z + w.w * xx.w;
        }
        #pragma unroll
        for (int off = 32; off; off >>= 1) a += __shfl_down(a, off, 64);
        if (lane == 0) {
            const float u = a + b[row];
            const float r = fmaxf(u, 0.f);
            const float zz = r * r;              // z = relu(u)^2 (LAMB = 2)
            sz[wv] = zz;
            z_out[row] = zz;
        }
    }
    __syncthreads();                             // tile + sz ready

    // ---- Stage B: prefetch sub-batch 1 to regs; accumulate sub-batch 0 ----
    float4 r1[16];                               // 64 VGPRs, statically indexed
    const int row1 = k0 + SUB + wv;
    {
        const float4* Wr1 = reinterpret_cast<const float4*>(W + (size_t)row1 * D);
        #pragma unroll
        for (int q = 0; q < 16; ++q) r1[q] = Wr1[lane + q * 64];  // issue early
    }
    #pragma unroll
    for (int c4 = 0; c4 < 4; ++c4) {             // hides the loads above
        const int col = tid + c4 * 256;
        #pragma unroll
        for (int r = 0; r < SUB; ++r) {
            const float4 w = tile[r * 1024 + col];
            const float zz = sz[r];
            acc[c4].x += zz * w.x; acc[c4].y += zz * w.y;
            acc[c4].z += zz * w.z; acc[c4].w += zz * w.w;
        }
    }
    float a1 = 0.f;
    #pragma unroll
    for (int q = 0; q < 16; ++q) {
        const float4 xx = xv[lane + q * 64];
        a1 += r1[q].x * xx.x + r1[q].y * xx.y + r1[q].z * xx.z + r1[q].w * xx.w;
    }
    __syncthreads();                             // done reading tile (sb0)

    // ---- Stage C: sub-batch 1 -> tile; z ----
    #pragma unroll
    for (int q = 0; q < 16; ++q) tile[wv * 1024 + lane + q * 64] = r1[q];
    #pragma unroll
    for (int off = 32; off; off >>= 1) a1 += __shfl_down(a1, off, 64);
    if (lane == 0) {
        const float u = a1 + b[row1];
        const float r = fmaxf(u, 0.f);
        const float zz = r * r;
        sz[wv] = zz;
        z_out[row1] = zz;
    }
    __syncthreads();

    // ---- Stage D: accumulate sub-batch 1; plain P store ----
    #pragma unroll
    for (int c4 = 0; c4 < 4; ++c4) {
        const int col = tid + c4 * 256;
        #pragma unroll
        for (int r = 0; r < SUB; ++r) {
            const float4 w = tile[r * 1024 + col];
            const float zz = sz[r];
            acc[c4].x += zz * w.x; acc[c4].y += zz * w.y;
            acc[c4].z += zz * w.z; acc[c4].w += zz * w.w;
        }
    }
    float4* Pp = reinterpret_cast<float4*>(P + (size_t)c * D);
    #pragma unroll
    for (int c4 = 0; c4 < 4; ++c4) Pp[tid + c4 * 256] = acc[c4];
}

// ---------------------------------------------------------------------------
// K2: group super-sums (128 parallel blocks) + ONE stats block with a
// SINGLE fused pass: max(z), sum(z), sum(ea) reduced simultaneously;
// sum(ea_new) = GAMMA*Sea + (1-GAMMA)*Sz/m^2 (avg impact ~1e-8 on gf).
// Writes y / ea outputs and gfp/gfn/sc for k_update.
// ---------------------------------------------------------------------------
__global__ __launch_bounds__(256) void k_mid(const float* __restrict__ P,
                                             const float* __restrict__ z,
                                             const float* __restrict__ ea,
                                             float* __restrict__ SS,
                                             float* __restrict__ y_out,
                                             float* __restrict__ ea_out,
                                             float* __restrict__ gfp,
                                             float* __restrict__ gfn,
                                             float* __restrict__ sc) {
    const int tid = threadIdx.x;
    const int g   = blockIdx.y;
    const int bx  = blockIdx.x;

    if (g < NSS) {                         // super-sum block
        const int j4 = bx * 256 + tid;
        const float4* Pp = reinterpret_cast<const float4*>(P)
                         + (size_t)(g * GSZ2) * (D / 4) + j4;
        float4 a = make_float4(0.f, 0.f, 0.f, 0.f);
        #pragma unroll
        for (int i = 0; i < GSZ2; ++i) {
            const float4 p = Pp[(size_t)i * (D / 4)];
            a.x += p.x; a.y += p.y; a.z += p.z; a.w += p.w;
        }
        reinterpret_cast<float4*>(SS)[(size_t)g * (D / 4) + j4] = a;
        return;
    }
    if (bx != 0) return;                   // stats: single block

    __shared__ float srm[4], srz[4], sre[4];
    __shared__ float sm[2];                // inv_m2, inv_avg
    const int wv   = tid >> 6;
    const int lane = tid & 63;

    // single fused pass over z / ea
    float lmax = 0.f, lsz = 0.f, lse = 0.f;
    #pragma unroll
    for (int i = 0; i < D / 256; ++i) {
        const int r = i * 256 + tid;
        const float zz = z[r];
        lmax = fmaxf(lmax, zz);
        lsz += zz;
        lse += ea[r];
    }
    #pragma unroll
    for (int off = 32; off; off >>= 1) {
        lmax = fmaxf(lmax, __shfl_down(lmax, off, 64));
        lsz += __shfl_down(lsz, off, 64);
        lse += __shfl_down(lse, off, 64);
    }
    if (lane == 0) { srm[wv] = lmax; srz[wv] = lsz; sre[wv] = lse; }
    __syncthreads();
    if (tid == 0) {
        const float m2 = fmaxf(fmaxf(srm[0], srm[1]), fmaxf(srm[2], srm[3]));
        const float Sz = (srz[0] + srz[1]) + (srz[2] + srz[3]);
        const float Se = (sre[0] + sre[1]) + (sre[2] + sre[3]);
        const float inv_m2 = 1.f / m2;
        sm[0] = inv_m2;
        sm[1] = (float)D / (GAMMA * Se + (1.f - GAMMA) * Sz * inv_m2);
    }
    __syncthreads();
    const float inv_m2  = sm[0];
    const float inv_avg = sm[1];

    #pragma unroll
    for (int i = 0; i < D / 256; ++i) {
        const int r = i * 256 + tid;
        const float yv = z[r] * inv_m2;
        const float ev = GAMMA * ea[r] + (1.f - GAMMA) * yv;
        const float gg = EPSC * tanhf(-EPSC * (ev * inv_avg - 1.f)) + 1.f;
        y_out[r]  = yv;
        ea_out[r] = ev;
        gfp[r]    = gg;
        gfn[r]    = 1.f / gg;
    }
    if (tid == 0) sc[0] = inv_m2;
}

// ---------------------------------------------------------------------------
// K3: minimal preamble (3 small loads, no scans/tanh) + two-level exclusive
// prefix (<=31 SS + <=12 P rows, L2-resident) + in-chunk inclusive scan +
// Hebbian delta + sign-split decay + nt W2 store.
// ---------------------------------------------------------------------------
__global__ __launch_bounds__(TPB3) void k_update(const float* __restrict__ W,
                                                 const float* __restrict__ x,
                                                 const float* __restrict__ z,
                                                 const float* __restrict__ P,
                                                 const float* __restrict__ SS,
                                                 const float* __restrict__ gfp,
                                                 const float* __restrict__ gfn,
                                                 const float* __restrict__ sc,
                                                 float* __restrict__ W2) {
    const int tid = threadIdx.x;
    const int t   = blockIdx.x;
    const int c   = blockIdx.y;            // 32-row chunk, 0..127
    const int j4  = t * TPB3 + tid;        // float4 column
    const int k0  = c * RCH3;

    __shared__ float sy[RCH3], sgp[RCH3], sgn[RCH3];
    const float inv_m2 = sc[0];
    if (tid < RCH3) {
        const int r = k0 + tid;
        sy[tid]  = z[r] * inv_m2;          // y = z / m^2
        sgp[tid] = gfp[r];
        sgn[tid] = gfn[r];
    }
    __syncthreads();

    // two-level exclusive prefix in z-units.
    const int g3 = c >> 2;                 // full SS groups (16 P rows each)
    float4 a0 = make_float4(0.f, 0.f, 0.f, 0.f);
    float4 a1 = make_float4(0.f, 0.f, 0.f, 0.f);
    {
        const float4* SSp = reinterpret_cast<const float4*>(SS) + j4;
        int i = 0;
        #pragma unroll 4
        for (; i + 2 <= g3; i += 2) {
            const float4 p0 = SSp[(size_t)i * (D / 4)];
            const float4 p1 = SSp[(size_t)(i + 1) * (D / 4)];
            a0.x += p0.x; a0.y += p0.y; a0.z += p0.z; a0.w += p0.w;
            a1.x += p1.x; a1.y += p1.y; a1.z += p1.z; a1.w += p1.w;
        }
        if (i < g3) {
            const float4 p0 = SSp[(size_t)i * (D / 4)];
            a0.x += p0.x; a0.y += p0.y; a0.z += p0.z; a0.w += p0.w;
        }
    }
    {
        const float4* Pp = reinterpret_cast<const float4*>(P) + j4;
        int i = g3 * GSZ2;
        const int iend = 4 * c;            // P rows before this 32-row chunk
        #pragma unroll 4
        for (; i + 2 <= iend; i += 2) {
            const float4 p0 = Pp[(size_t)i * (D / 4)];
            const float4 p1 = Pp[(size_t)(i + 1) * (D / 4)];
            a0.x += p0.x; a0.y += p0.y; a0.z += p0.z; a0.w += p0.w;
            a1.x += p1.x; a1.y += p1.y; a1.z += p1.z; a1.w += p1.w;
        }
        if (i < iend) {
            const float4 p0 = Pp[(size_t)i * (D / 4)];
            a0.x += p0.x; a0.y += p0.y; a0.z += p0.z; a0.w += p0.w;
        }
    }
    float4 s;                               // prefix converted to y-units
    s.x = (a0.x + a1.x) * inv_m2; s.y = (a0.y + a1.y) * inv_m2;
    s.z = (a0.z + a1.z) * inv_m2; s.w = (a0.w + a1.w) * inv_m2;

    const float4 xvv = reinterpret_cast<const float4*>(x)[j4];
    const float4* Wp  = reinterpret_cast<const float4*>(W  + (size_t)k0 * D) + j4;
    float4*       W2p = reinterpret_cast<float4*>(W2 + (size_t)k0 * D) + j4;
    #pragma unroll 4
    for (int k = 0; k < RCH3; ++k) {
        const float yv = sy[k];
        const float gp = sgp[k];
        const float gn = sgn[k];
        const float4 w = Wp[(size_t)k * (D / 4)];
        s.x += yv * w.x; s.y += yv * w.y;
        s.z += yv * w.z; s.w += yv * w.w;
        vf4 o;
        {
            const float w1 = w.x + ALPHA * (yv * xvv.x - yv * s.x);
            o.x = w1 * (w1 > 0.f ? gp : gn);
        }
        {
            const float w1 = w.y + ALPHA * (yv * xvv.y - yv * s.y);
            o.y = w1 * (w1 > 0.f ? gp : gn);
        }
        {
            const float w1 = w.z + ALPHA * (yv * xvv.z - yv * s.z);
            o.z = w1 * (w1 > 0.f ? gp : gn);
        }
        {
            const float w1 = w.w + ALPHA * (yv * xvv.w - yv * s.w);
            o.w = w1 * (w1 > 0.f ? gp : gn);
        }
        __builtin_nontemporal_store(o, reinterpret_cast<vf4*>(W2p + (size_t)k * (D / 4)));
    }
}

// ===========================================================================
// Fallback (proven R6-style structure) if ws_size can't hold the 8.5 MB P/SS.
// ===========================================================================
constexpr int FCH  = 64;
constexpr int FNCH = D / FCH;
constexpr int FTPB = 128;

__global__ __launch_bounds__(256) void f_gemv(const float* __restrict__ W,
                                              const float* __restrict__ x,
                                              const float* __restrict__ b,
                                              float* __restrict__ u) {
    const int wave = threadIdx.x >> 6;
    const int lane = threadIdx.x & 63;
    const int row  = (blockIdx.x << 2) + wave;
    const float4* Wr = reinterpret_cast<const float4*>(W + (size_t)row * D);
    const float4* xv = reinterpret_cast<const float4*>(x);
    float acc = 0.f;
    #pragma unroll
    for (int it = 0; it < D / 256; ++it) {
        const float4 w  = Wr[lane + it * 64];
        const float4 xx = xv[lane + it * 64];
        acc += w.x * xx.x + w.y * xx.y + w.z * xx.z + w.w * xx.w;
    }
    #pragma unroll
    for (int off = 32; off; off >>= 1) acc += __shfl_down(acc, off, 64);
    if (lane == 0) u[row] = acc + b[row];
}

__global__ __launch_bounds__(FTPB) void f_pstats(const float* __restrict__ u,
                                                 const float* __restrict__ ea,
                                                 const float* __restrict__ W,
                                                 float* __restrict__ y_out,
                                                 float* __restrict__ ea_out,
                                                 float* __restrict__ gfp,
                                                 float* __restrict__ gfn,
                                                 float* __restrict__ P) {
    const int tid  = threadIdx.x;
    const int t    = blockIdx.x;
    const int c    = blockIdx.y;
    const int j    = t * (FTPB * 4) + tid * 4;
    const int k0   = c * FCH;
    const int wv   = tid >> 6;
    const int lane = tid & 63;

    __shared__ float sred[2];
    __shared__ float sm[2];
    __shared__ float sy[FCH];

    float lmax = 0.f;
    #pragma unroll
    for (int i = 0; i < D / FTPB; ++i)
        lmax = fmaxf(lmax, u[i * FTPB + tid]);
    #pragma unroll
    for (int off = 32; off; off >>= 1) lmax = fmaxf(lmax, __shfl_down(lmax, off, 64));
    if (lane == 0) sred[wv] = lmax;
    __syncthreads();
    if (tid == 0) sm[0] = fmaxf(sred[0], sred[1]);
    __syncthreads();
    const float m = sm[0];
    const float inv_m2 = 1.f / (m * m);

    float lsum = 0.f;
    #pragma unroll
    for (int i = 0; i < D / FTPB; ++i) {
        const int r  = i * FTPB + tid;
        const float rr = fmaxf(u[r], 0.f);
        lsum += GAMMA * ea[r] + (1.f - GAMMA) * (rr * rr * inv_m2);
    }
    #pragma unroll
    for (int off = 32; off; off >>= 1) lsum += __shfl_down(lsum, off, 64);
    if (lane == 0) sred[wv] = lsum;
    __syncthreads();
    if (tid == 0) sm[1] = sred[0] + sred[1];
    __syncthreads();
    const float inv_avg = (float)D / sm[1];

    if (tid < FCH) {
        const int r = k0 + tid;
        const float rr = fmaxf(u[r], 0.f);
        const float yv = rr * rr * inv_m2;
        sy[tid] = yv;
        if (t == 0) {
            const float ev = GAMMA * ea[r] + (1.f - GAMMA) * yv;
            const float a  = ev * inv_avg;
            const float g  = EPSC * tanhf(-EPSC * (a - 1.f)) + 1.f;
            y_out[r]  = yv;
            ea_out[r] = ev;
            gfp[r]    = g;
            gfn[r]    = 1.f / g;
        }
    }
    __syncthreads();

    const float4* Wp = reinterpret_cast<const float4*>(W + (size_t)k0 * D + j);
    float4 acc = make_float4(0.f, 0.f, 0.f, 0.f);
    #pragma unroll 8
    for (int k = 0; k < FCH; ++k) {
        const float yv = sy[k];
        const float4 w = Wp[(size_t)k * (D / 4)];
        acc.x += yv * w.x; acc.y += yv * w.y;
        acc.z += yv * w.z; acc.w += yv * w.w;
    }
    *reinterpret_cast<float4*>(P + (size_t)c * D + j) = acc;
}

__global__ __launch_bounds__(FTPB) void f_update(const float* __restrict__ W,
                                                 const float* __restrict__ x,
                                                 const float* __restrict__ y,
                                                 const float* __restrict__ P,
                                                 const float* __restrict__ gfp,
                                                 const float* __restrict__ gfn,
                                                 float* __restrict__ W2) {
    const int tid = threadIdx.x;
    const int j   = blockIdx.x * (FTPB * 4) + tid * 4;
    const int c   = blockIdx.y;
    const int k0  = c * FCH;

    __shared__ float sy[FCH], sgp[FCH], sgn[FCH];
    if (tid < FCH) {
        const int r = k0 + tid;
        sy[tid]  = y[r];
        sgp[tid] = gfp[r];
        sgn[tid] = gfn[r];
    }
    __syncthreads();

    const float4* Pp = reinterpret_cast<const float4*>(P + j);
    float4 a0 = make_float4(0.f, 0.f, 0.f, 0.f);
    float4 a1 = make_float4(0.f, 0.f, 0.f, 0.f);
    int i = 0;
    #pragma unroll 8
    for (; i + 2 <= c; i += 2) {
        const float4 p0 = Pp[(size_t)i * (D / 4)];
        const float4 p1 = Pp[(size_t)(i + 1) * (D / 4)];
        a0.x += p0.x; a0.y += p0.y; a0.z += p0.z; a0.w += p0.w;
        a1.x += p1.x; a1.y += p1.y; a1.z += p1.z; a1.w += p1.w;
    }
    if (i < c) {
        const float4 p0 = Pp[(size_t)i * (D / 4)];
        a0.x += p0.x; a0.y += p0.y; a0.z += p0.z; a0.w += p0.w;
    }
    float4 s;
    s.x = a0.x + a1.x; s.y = a0.y + a1.y;
    s.z = a0.z + a1.z; s.w = a0.w + a1.w;

    const float4 xv = *reinterpret_cast<const float4*>(x + j);
    const float4* Wp  = reinterpret_cast<const float4*>(W + (size_t)k0 * D + j);
    float4*       W2p = reinterpret_cast<float4*>(W2 + (size_t)k0 * D + j);
    #pragma unroll 4
    for (int k = 0; k < FCH; ++k) {
        const float yv = sy[k];
        const float gp = sgp[k];
        const float gn = sgn[k];
        const float4 w = Wp[(size_t)k * (D / 4)];
        s.x += yv * w.x; s.y += yv * w.y;
        s.z += yv * w.z; s.w += yv * w.w;
        vf4 o;
        { const float w1 = w.x + ALPHA * (yv * xv.x - yv * s.x); o.x = w1 * (w1 > 0.f ? gp : gn); }
        { const float w1 = w.y + ALPHA * (yv * xv.y - yv * s.y); o.y = w1 * (w1 > 0.f ? gp : gn); }
        { const float w1 = w.z + ALPHA * (yv * xv.z - yv * s.z); o.z = w1 * (w1 > 0.f ? gp : gn); }
        { const float w1 = w.w + ALPHA * (yv * xv.w - yv * s.w); o.w = w1 * (w1 > 0.f ? gp : gn); }
        __builtin_nontemporal_store(o, reinterpret_cast<vf4*>(W2p + (size_t)k * (D / 4)));
    }
}

// ===========================================================================
extern "C" void kernel_launch(void* const* d_in, const int* in_sizes, int n_in,
                              void* d_out, int out_size, void* d_ws, size_t ws_size,
                              hipStream_t stream) {
    const float* x  = (const float*)d_in[0];
    const float* W  = (const float*)d_in[1];
    const float* b  = (const float*)d_in[2];
    const float* ea = (const float*)d_in[3];

    float* out    = (float*)d_out;
    float* y_out  = out;                        // [D]
    float* W2_out = out + D;                    // [D*D]
    float* ea_out = out + D + (size_t)D * D;    // [D]

    float* ws = (float*)d_ws;
    const size_t need = (size_t)(3 * D + 16 + (size_t)NPR * D + (size_t)NSS * D)
                        * sizeof(float);

    if (ws_size >= need) {
        float* z   = ws;                        // [D]
        float* gfp = z + D;                     // [D]
        float* gfn = gfp + D;                   // [D]
        float* sc  = gfn + D;                   // [16]
        float* P   = sc + 16;                   // [NPR * D]  8 MB
        float* SS  = P + (size_t)NPR * D;       // [NSS * D]  512 KB

        k_gz<<<NPR, 256, 0, stream>>>(W, x, b, z, P);
        k_mid<<<dim3(4, NSS + 1), 256, 0, stream>>>(P, z, ea, SS, y_out, ea_out,
                                                    gfp, gfn, sc);
        k_update<<<dim3(4, NCH3), TPB3, 0, stream>>>(W, x, z, P, SS,
                                                     gfp, gfn, sc, W2_out);
    } else {
        float* u   = ws;                        // [D]
        float* gfp = ws + D;                    // [D]
        float* gfn = ws + 2 * D;                // [D]
        float* P   = ws + 3 * D;                // [FNCH * D] = 1 MB

        f_gemv<<<D / 4, 256, 0, stream>>>(W, x, b, u);
        dim3 grid(D / (FTPB * 4), FNCH);
        f_pstats<<<grid, FTPB, 0, stream>>>(u, ea, W, y_out, ea_out, gfp, gfn, P);
        f_update<<<grid, FTPB, 0, stream>>>(W, x, y_out, P, gfp, gfn, W2_out);
    }
}

// Round 14
// 44.491 us; speedup vs baseline: 1.0635x; 1.0635x over previous
//
#include <hip/hip_runtime.h>
#include <math.h>

// Problem constants (D_IN == D_OUT == 4096)
constexpr int   D     = 4096;
constexpr float ALPHA = 0.001f;   // heb_lr
constexpr float GAMMA = 0.99f;
constexpr float EPSC  = 0.0001f;

// --- main path decomposition ---
constexpr int RG    = 8;               // rows per k_gz block (P granularity)
constexpr int NPR   = D / RG;          // 512 P rows
constexpr int SUB   = 4;               // rows per LDS sub-batch (64 KB tile)
constexpr int GSZ2  = 16;              // P rows per supersum group
constexpr int NSS   = NPR / GSZ2;      // 32 SS rows
constexpr int RCH3  = 32;              // k_update rows per chunk
constexpr int NCH3  = D / RCH3;        // 128 -> 512 blocks
constexpr int TPB3  = 256;

using vf4 = float __attribute__((ext_vector_type(4)));

// ---------------------------------------------------------------------------
// K1 (R12-proven, unchanged): fused GEMV + chunk column-partials via LDS
// staging (z-units), register prefetch of sub-batch 1 under sub-batch 0's
// LDS accumulate. Plain P stores. W read from HBM exactly once.
// ---------------------------------------------------------------------------
__global__ __launch_bounds__(256, 2) void k_gz(const float* __restrict__ W,
                                               const float* __restrict__ x,
                                               const float* __restrict__ b,
                                               float* __restrict__ z_out,
                                               float* __restrict__ P) {
    const int tid  = threadIdx.x;
    const int lane = tid & 63;
    const int wv   = tid >> 6;            // 0..3
    const int c    = blockIdx.x;          // P row (8-row chunk)
    const int k0   = c * RG;

    __shared__ float4 tile[SUB * 1024];   // 64 KB
    __shared__ float  sz[SUB];

    const float4* xv = reinterpret_cast<const float4*>(x);
    float4 acc[4] = {make_float4(0.f, 0.f, 0.f, 0.f),
                     make_float4(0.f, 0.f, 0.f, 0.f),
                     make_float4(0.f, 0.f, 0.f, 0.f),
                     make_float4(0.f, 0.f, 0.f, 0.f)};

    // ---- Stage A: sub-batch 0 -> tile + dot ----
    {
        const int row = k0 + wv;
        const float4* Wr = reinterpret_cast<const float4*>(W + (size_t)row * D);
        float a = 0.f;
        #pragma unroll
        for (int q = 0; q < 16; ++q) {
            const float4 w = Wr[lane + q * 64];
            tile[wv * 1024 + lane + q * 64] = w;
            const float4 xx = xv[lane + q * 64];
            a += w.x * xx.x + w.y * xx.y + w.z * xx.z + w.w * xx.w;
        }
        #pragma unroll
        for (int off = 32; off; off >>= 1) a += __shfl_down(a, off, 64);
        if (lane == 0) {
            const float u = a + b[row];
            const float r = fmaxf(u, 0.f);
            const float zz = r * r;              // z = relu(u)^2 (LAMB = 2)
            sz[wv] = zz;
            z_out[row] = zz;
        }
    }
    __syncthreads();                             // tile + sz ready

    // ---- Stage B: prefetch sub-batch 1 to regs; accumulate sub-batch 0 ----
    float4 r1[16];                               // 64 VGPRs, statically indexed
    const int row1 = k0 + SUB + wv;
    {
        const float4* Wr1 = reinterpret_cast<const float4*>(W + (size_t)row1 * D);
        #pragma unroll
        for (int q = 0; q < 16; ++q) r1[q] = Wr1[lane + q * 64];  // issue early
    }
    #pragma unroll
    for (int c4 = 0; c4 < 4; ++c4) {             // hides the loads above
        const int col = tid + c4 * 256;
        #pragma unroll
        for (int r = 0; r < SUB; ++r) {
            const float4 w = tile[r * 1024 + col];
            const float zz = sz[r];
            acc[c4].x += zz * w.x; acc[c4].y += zz * w.y;
            acc[c4].z += zz * w.z; acc[c4].w += zz * w.w;
        }
    }
    float a1 = 0.f;
    #pragma unroll
    for (int q = 0; q < 16; ++q) {
        const float4 xx = xv[lane + q * 64];
        a1 += r1[q].x * xx.x + r1[q].y * xx.y + r1[q].z * xx.z + r1[q].w * xx.w;
    }
    __syncthreads();                             // done reading tile (sb0)

    // ---- Stage C: sub-batch 1 -> tile; z ----
    #pragma unroll
    for (int q = 0; q < 16; ++q) tile[wv * 1024 + lane + q * 64] = r1[q];
    #pragma unroll
    for (int off = 32; off; off >>= 1) a1 += __shfl_down(a1, off, 64);
    if (lane == 0) {
        const float u = a1 + b[row1];
        const float r = fmaxf(u, 0.f);
        const float zz = r * r;
        sz[wv] = zz;
        z_out[row1] = zz;
    }
    __syncthreads();

    // ---- Stage D: accumulate sub-batch 1; plain P store ----
    #pragma unroll
    for (int c4 = 0; c4 < 4; ++c4) {
        const int col = tid + c4 * 256;
        #pragma unroll
        for (int r = 0; r < SUB; ++r) {
            const float4 w = tile[r * 1024 + col];
            const float zz = sz[r];
            acc[c4].x += zz * w.x; acc[c4].y += zz * w.y;
            acc[c4].z += zz * w.z; acc[c4].w += zz * w.w;
        }
    }
    float4* Pp = reinterpret_cast<float4*>(P + (size_t)c * D);
    #pragma unroll
    for (int c4 = 0; c4 < 4; ++c4) Pp[tid + c4 * 256] = acc[c4];
}

// ---------------------------------------------------------------------------
// K2 (R12-proven, unchanged): pure group super-sums. 128 blocks, ~1 us.
// ---------------------------------------------------------------------------
__global__ __launch_bounds__(256) void k_ss(const float* __restrict__ P,
                                            float* __restrict__ SS) {
    const int j4 = blockIdx.x * 256 + threadIdx.x;   // float4 column
    const int g  = blockIdx.y;
    const float4* Pp = reinterpret_cast<const float4*>(P)
                     + (size_t)(g * GSZ2) * (D / 4) + j4;
    float4 a = make_float4(0.f, 0.f, 0.f, 0.f);
    #pragma unroll
    for (int i = 0; i < GSZ2; ++i) {
        const float4 p = Pp[(size_t)i * (D / 4)];
        a.x += p.x; a.y += p.y; a.z += p.z; a.w += p.w;
    }
    reinterpret_cast<float4*>(SS)[(size_t)g * (D / 4) + j4] = a;
}

// ---------------------------------------------------------------------------
// K3 (R12 base; R14 change: SINGLE fused stats pass): max(z), sum(z),
// sum(ea) reduced simultaneously -- halves the preamble's z/ea traffic and
// removes the pass-1 -> pass-2 dependency. sum(ea_new) = GAMMA*Sea +
// (1-GAMMA)*Sz/m^2 (avg impact ~1e-8 on gf; reduction order identical
// across blocks -> bitwise-consistent). Then two-level exclusive prefix,
// in-chunk inclusive scan, Hebbian delta + sign-split decay, nt W2 store.
// t==0 blocks write y/ea outputs.
// ---------------------------------------------------------------------------
__global__ __launch_bounds__(TPB3) void k_update(const float* __restrict__ W,
                                                 const float* __restrict__ x,
                                                 const float* __restrict__ z,
                                                 const float* __restrict__ ea,
                                                 const float* __restrict__ P,
                                                 const float* __restrict__ SS,
                                                 float* __restrict__ y_out,
                                                 float* __restrict__ ea_out,
                                                 float* __restrict__ W2) {
    const int tid  = threadIdx.x;
    const int t    = blockIdx.x;
    const int c    = blockIdx.y;           // 32-row chunk, 0..127
    const int j4   = t * TPB3 + tid;       // float4 column
    const int k0   = c * RCH3;
    const int wv   = tid >> 6;
    const int lane = tid & 63;

    __shared__ float srm[4], srz[4], sre[4];
    __shared__ float sm[2];                // inv_m2, inv_avg
    __shared__ float sy[RCH3], sgp[RCH3], sgn[RCH3];

    // single fused stats pass: max(z), sum(z), sum(ea)
    float lmax = 0.f, lsz = 0.f, lse = 0.f;
    #pragma unroll
    for (int i = 0; i < D / TPB3; ++i) {
        const int r = i * TPB3 + tid;
        const float zz = z[r];
        lmax = fmaxf(lmax, zz);
        lsz += zz;
        lse += ea[r];
    }
    #pragma unroll
    for (int off = 32; off; off >>= 1) {
        lmax = fmaxf(lmax, __shfl_down(lmax, off, 64));
        lsz += __shfl_down(lsz, off, 64);
        lse += __shfl_down(lse, off, 64);
    }
    if (lane == 0) { srm[wv] = lmax; srz[wv] = lsz; sre[wv] = lse; }
    __syncthreads();
    if (tid == 0) {
        const float m2 = fmaxf(fmaxf(srm[0], srm[1]), fmaxf(srm[2], srm[3]));
        const float Sz = (srz[0] + srz[1]) + (srz[2] + srz[3]);
        const float Se = (sre[0] + sre[1]) + (sre[2] + sre[3]);
        const float inv_m2 = 1.f / m2;
        sm[0] = inv_m2;
        sm[1] = (float)D / (GAMMA * Se + (1.f - GAMMA) * Sz * inv_m2);
    }
    __syncthreads();
    const float inv_m2  = sm[0];
    const float inv_avg = sm[1];

    // own-chunk y / gf; t==0 blocks write y / ea globals
    if (tid < RCH3) {
        const int r = k0 + tid;
        const float yv = z[r] * inv_m2;
        const float ev = GAMMA * ea[r] + (1.f - GAMMA) * yv;
        const float gg = EPSC * tanhf(-EPSC * (ev * inv_avg - 1.f)) + 1.f;
        sy[tid]  = yv;
        sgp[tid] = gg;
        sgn[tid] = 1.f / gg;
        if (t == 0) { y_out[r] = yv; ea_out[r] = ev; }
    }
    __syncthreads();

    // two-level exclusive prefix in z-units.
    const int g3 = c >> 2;                 // full SS groups (16 P rows each)
    float4 a0 = make_float4(0.f, 0.f, 0.f, 0.f);
    float4 a1 = make_float4(0.f, 0.f, 0.f, 0.f);
    {
        const float4* SSp = reinterpret_cast<const float4*>(SS) + j4;
        int i = 0;
        #pragma unroll 4
        for (; i + 2 <= g3; i += 2) {
            const float4 p0 = SSp[(size_t)i * (D / 4)];
            const float4 p1 = SSp[(size_t)(i + 1) * (D / 4)];
            a0.x += p0.x; a0.y += p0.y; a0.z += p0.z; a0.w += p0.w;
            a1.x += p1.x; a1.y += p1.y; a1.z += p1.z; a1.w += p1.w;
        }
        if (i < g3) {
            const float4 p0 = SSp[(size_t)i * (D / 4)];
            a0.x += p0.x; a0.y += p0.y; a0.z += p0.z; a0.w += p0.w;
        }
    }
    {
        const float4* Pp = reinterpret_cast<const float4*>(P) + j4;
        int i = g3 * GSZ2;
        const int iend = 4 * c;            // P rows before this 32-row chunk
        #pragma unroll 4
        for (; i + 2 <= iend; i += 2) {
            const float4 p0 = Pp[(size_t)i * (D / 4)];
            const float4 p1 = Pp[(size_t)(i + 1) * (D / 4)];
            a0.x += p0.x; a0.y += p0.y; a0.z += p0.z; a0.w += p0.w;
            a1.x += p1.x; a1.y += p1.y; a1.z += p1.z; a1.w += p1.w;
        }
        if (i < iend) {
            const float4 p0 = Pp[(size_t)i * (D / 4)];
            a0.x += p0.x; a0.y += p0.y; a0.z += p0.z; a0.w += p0.w;
        }
    }
    float4 s;                               // prefix converted to y-units
    s.x = (a0.x + a1.x) * inv_m2; s.y = (a0.y + a1.y) * inv_m2;
    s.z = (a0.z + a1.z) * inv_m2; s.w = (a0.w + a1.w) * inv_m2;

    const float4 xvv = reinterpret_cast<const float4*>(x)[j4];
    const float4* Wp  = reinterpret_cast<const float4*>(W  + (size_t)k0 * D) + j4;
    float4*       W2p = reinterpret_cast<float4*>(W2 + (size_t)k0 * D) + j4;
    #pragma unroll 4
    for (int k = 0; k < RCH3; ++k) {
        const float yv = sy[k];
        const float gp = sgp[k];
        const float gn = sgn[k];
        const float4 w = Wp[(size_t)k * (D / 4)];
        s.x += yv * w.x; s.y += yv * w.y;
        s.z += yv * w.z; s.w += yv * w.w;
        vf4 o;
        {
            const float w1 = w.x + ALPHA * (yv * xvv.x - yv * s.x);
            o.x = w1 * (w1 > 0.f ? gp : gn);
        }
        {
            const float w1 = w.y + ALPHA * (yv * xvv.y - yv * s.y);
            o.y = w1 * (w1 > 0.f ? gp : gn);
        }
        {
            const float w1 = w.z + ALPHA * (yv * xvv.z - yv * s.z);
            o.z = w1 * (w1 > 0.f ? gp : gn);
        }
        {
            const float w1 = w.w + ALPHA * (yv * xvv.w - yv * s.w);
            o.w = w1 * (w1 > 0.f ? gp : gn);
        }
        __builtin_nontemporal_store(o, reinterpret_cast<vf4*>(W2p + (size_t)k * (D / 4)));
    }
}

// ===========================================================================
// Fallback (proven R6-style structure) if ws_size can't hold the 8.5 MB P/SS.
// ===========================================================================
constexpr int FCH  = 64;
constexpr int FNCH = D / FCH;
constexpr int FTPB = 128;

__global__ __launch_bounds__(256) void f_gemv(const float* __restrict__ W,
                                              const float* __restrict__ x,
                                              const float* __restrict__ b,
                                              float* __restrict__ u) {
    const int wave = threadIdx.x >> 6;
    const int lane = threadIdx.x & 63;
    const int row  = (blockIdx.x << 2) + wave;
    const float4* Wr = reinterpret_cast<const float4*>(W + (size_t)row * D);
    const float4* xv = reinterpret_cast<const float4*>(x);
    float acc = 0.f;
    #pragma unroll
    for (int it = 0; it < D / 256; ++it) {
        const float4 w  = Wr[lane + it * 64];
        const float4 xx = xv[lane + it * 64];
        acc += w.x * xx.x + w.y * xx.y + w.z * xx.z + w.w * xx.w;
    }
    #pragma unroll
    for (int off = 32; off; off >>= 1) acc += __shfl_down(acc, off, 64);
    if (lane == 0) u[row] = acc + b[row];
}

__global__ __launch_bounds__(FTPB) void f_pstats(const float* __restrict__ u,
                                                 const float* __restrict__ ea,
                                                 const float* __restrict__ W,
                                                 float* __restrict__ y_out,
                                                 float* __restrict__ ea_out,
                                                 float* __restrict__ gfp,
                                                 float* __restrict__ gfn,
                                                 float* __restrict__ P) {
    const int tid  = threadIdx.x;
    const int t    = blockIdx.x;
    const int c    = blockIdx.y;
    const int j    = t * (FTPB * 4) + tid * 4;
    const int k0   = c * FCH;
    const int wv   = tid >> 6;
    const int lane = tid & 63;

    __shared__ float sred[2];
    __shared__ float sm[2];
    __shared__ float sy[FCH];

    float lmax = 0.f;
    #pragma unroll
    for (int i = 0; i < D / FTPB; ++i)
        lmax = fmaxf(lmax, u[i * FTPB + tid]);
    #pragma unroll
    for (int off = 32; off; off >>= 1) lmax = fmaxf(lmax, __shfl_down(lmax, off, 64));
    if (lane == 0) sred[wv] = lmax;
    __syncthreads();
    if (tid == 0) sm[0] = fmaxf(sred[0], sred[1]);
    __syncthreads();
    const float m = sm[0];
    const float inv_m2 = 1.f / (m * m);

    float lsum = 0.f;
    #pragma unroll
    for (int i = 0; i < D / FTPB; ++i) {
        const int r  = i * FTPB + tid;
        const float rr = fmaxf(u[r], 0.f);
        lsum += GAMMA * ea[r] + (1.f - GAMMA) * (rr * rr * inv_m2);
    }
    #pragma unroll
    for (int off = 32; off; off >>= 1) lsum += __shfl_down(lsum, off, 64);
    if (lane == 0) sred[wv] = lsum;
    __syncthreads();
    if (tid == 0) sm[1] = sred[0] + sred[1];
    __syncthreads();
    const float inv_avg = (float)D / sm[1];

    if (tid < FCH) {
        const int r = k0 + tid;
        const float rr = fmaxf(u[r], 0.f);
        const float yv = rr * rr * inv_m2;
        sy[tid] = yv;
        if (t == 0) {
            const float ev = GAMMA * ea[r] + (1.f - GAMMA) * yv;
            const float a  = ev * inv_avg;
            const float g  = EPSC * tanhf(-EPSC * (a - 1.f)) + 1.f;
            y_out[r]  = yv;
            ea_out[r] = ev;
            gfp[r]    = g;
            gfn[r]    = 1.f / g;
        }
    }
    __syncthreads();

    const float4* Wp = reinterpret_cast<const float4*>(W + (size_t)k0 * D + j);
    float4 acc = make_float4(0.f, 0.f, 0.f, 0.f);
    #pragma unroll 8
    for (int k = 0; k < FCH; ++k) {
        const float yv = sy[k];
        const float4 w = Wp[(size_t)k * (D / 4)];
        acc.x += yv * w.x; acc.y += yv * w.y;
        acc.z += yv * w.z; acc.w += yv * w.w;
    }
    *reinterpret_cast<float4*>(P + (size_t)c * D + j) = acc;
}

__global__ __launch_bounds__(FTPB) void f_update(const float* __restrict__ W,
                                                 const float* __restrict__ x,
                                                 const float* __restrict__ y,
                                                 const float* __restrict__ P,
                                                 const float* __restrict__ gfp,
                                                 const float* __restrict__ gfn,
                                                 float* __restrict__ W2) {
    const int tid = threadIdx.x;
    const int j   = blockIdx.x * (FTPB * 4) + tid * 4;
    const int c   = blockIdx.y;
    const int k0  = c * FCH;

    __shared__ float sy[FCH], sgp[FCH], sgn[FCH];
    if (tid < FCH) {
        const int r = k0 + tid;
        sy[tid]  = y[r];
        sgp[tid] = gfp[r];
        sgn[tid] = gfn[r];
    }
    __syncthreads();

    const float4* Pp = reinterpret_cast<const float4*>(P + j);
    float4 a0 = make_float4(0.f, 0.f, 0.f, 0.f);
    float4 a1 = make_float4(0.f, 0.f, 0.f, 0.f);
    int i = 0;
    #pragma unroll 8
    for (; i + 2 <= c; i += 2) {
        const float4 p0 = Pp[(size_t)i * (D / 4)];
        const float4 p1 = Pp[(size_t)(i + 1) * (D / 4)];
        a0.x += p0.x; a0.y += p0.y; a0.z += p0.z; a0.w += p0.w;
        a1.x += p1.x; a1.y += p1.y; a1.z += p1.z; a1.w += p1.w;
    }
    if (i < c) {
        const float4 p0 = Pp[(size_t)i * (D / 4)];
        a0.x += p0.x; a0.y += p0.y; a0.z += p0.z; a0.w += p0.w;
    }
    float4 s;
    s.x = a0.x + a1.x; s.y = a0.y + a1.y;
    s.z = a0.z + a1.z; s.w = a0.w + a1.w;

    const float4 xv = *reinterpret_cast<const float4*>(x + j);
    const float4* Wp  = reinterpret_cast<const float4*>(W + (size_t)k0 * D + j);
    float4*       W2p = reinterpret_cast<float4*>(W2 + (size_t)k0 * D + j);
    #pragma unroll 4
    for (int k = 0; k < FCH; ++k) {
        const float yv = sy[k];
        const float gp = sgp[k];
        const float gn = sgn[k];
        const float4 w = Wp[(size_t)k * (D / 4)];
        s.x += yv * w.x; s.y += yv * w.y;
        s.z += yv * w.z; s.w += yv * w.w;
        vf4 o;
        { const float w1 = w.x + ALPHA * (yv * xv.x - yv * s.x); o.x = w1 * (w1 > 0.f ? gp : gn); }
        { const float w1 = w.y + ALPHA * (yv * xv.y - yv * s.y); o.y = w1 * (w1 > 0.f ? gp : gn); }
        { const float w1 = w.z + ALPHA * (yv * xv.z - yv * s.z); o.z = w1 * (w1 > 0.f ? gp : gn); }
        { const float w1 = w.w + ALPHA * (yv * xv.w - yv * s.w); o.w = w1 * (w1 > 0.f ? gp : gn); }
        __builtin_nontemporal_store(o, reinterpret_cast<vf4*>(W2p + (size_t)k * (D / 4)));
    }
}

// ===========================================================================
extern "C" void kernel_launch(void* const* d_in, const int* in_sizes, int n_in,
                              void* d_out, int out_size, void* d_ws, size_t ws_size,
                              hipStream_t stream) {
    const float* x  = (const float*)d_in[0];
    const float* W  = (const float*)d_in[1];
    const float* b  = (const float*)d_in[2];
    const float* ea = (const float*)d_in[3];

    float* out    = (float*)d_out;
    float* y_out  = out;                        // [D]
    float* W2_out = out + D;                    // [D*D]
    float* ea_out = out + D + (size_t)D * D;    // [D]

    float* ws = (float*)d_ws;
    const size_t need = (size_t)(D + (size_t)NPR * D + (size_t)NSS * D)
                        * sizeof(float);

    if (ws_size >= need) {
        float* z  = ws;                         // [D]         16 KB
        float* P  = z + D;                      // [NPR * D]   8 MB
        float* SS = P + (size_t)NPR * D;        // [NSS * D]   512 KB

        k_gz<<<NPR, 256, 0, stream>>>(W, x, b, z, P);
        k_ss<<<dim3(4, NSS), 256, 0, stream>>>(P, SS);
        k_update<<<dim3(4, NCH3), TPB3, 0, stream>>>(W, x, z, ea, P, SS,
                                                     y_out, ea_out, W2_out);
    } else {
        float* u   = ws;                        // [D]
        float* gfp = ws + D;                    // [D]
        float* gfn = ws + 2 * D;                // [D]
        float* P   = ws + 3 * D;                // [FNCH * D] = 1 MB

        f_gemv<<<D / 4, 256, 0, stream>>>(W, x, b, u);
        dim3 grid(D / (FTPB * 4), FNCH);
        f_pstats<<<grid, FTPB, 0, stream>>>(u, ea, W, y_out, ea_out, gfp, gfn, P);
        f_update<<<grid, FTPB, 0, stream>>>(W, x, y_out, P, gfp, gfn, W2_out);
    }
}